// Round 1
// baseline (254.133 us; speedup 1.0000x reference)
//
#include <hip/hip_runtime.h>
#include <hip/hip_bf16.h>

#define B_  8
#define NN  2048
#define D_  256
#define T_  1024
#define M1  20   // NUM_MUT + 1 classes

// ws layout (floats):
//  [0..7]  row_counts (per-b masked token counts)
//  [8]     loss accumulator
//  [9]     correct accumulator
//  [10]    mask-count accumulator
//  [11]    coords-is-int64 flag
//  [12]    mask-is-uint8 flag

__global__ __launch_bounds__(256) void setup_kernel(const unsigned int* __restrict__ coords_w,
                                                    const unsigned int* __restrict__ mask_w,
                                                    float* __restrict__ ws)
{
    __shared__ unsigned int s_odd_or;   // nonzero -> coords is int32
    __shared__ unsigned int s_gt1_or;   // nonzero -> mask is uint8 (packed bools)
    __shared__ float s_cnt[B_];
    int tid = threadIdx.x;
    if (tid == 0) { s_odd_or = 0u; s_gt1_or = 0u; }
    if (tid < B_) s_cnt[tid] = 0.f;
    __syncthreads();

    // Detect coords width: under int64 layout every odd 32-bit word (high half)
    // is zero (values are 0..2047). Under int32 they are random 0..2047.
    unsigned int odd = 0u;
    for (int i = tid; i < B_ * T_ / 2; i += 256) odd |= coords_w[2 * i + 1];
    // Detect mask layout: under uint8-bool layout, a 32-bit word packs 4 bools
    // (~80% ones) so some word > 1 almost surely. Under int32 all words are 0/1.
    unsigned int gt = 0u;
    for (int i = tid; i < B_ * T_ / 4; i += 256) gt |= (mask_w[i] > 1u) ? 1u : 0u;
    if (odd) atomicOr(&s_odd_or, 1u);
    if (gt)  atomicOr(&s_gt1_or, 1u);
    __syncthreads();

    bool mask_u8 = (s_gt1_or != 0u);
    const unsigned char* mask_b = (const unsigned char*)mask_w;

    for (int b = 0; b < B_; ++b) {
        float c = 0.f;
        for (int t = tid; t < T_; t += 256) {
            unsigned int mv = mask_u8 ? (unsigned int)mask_b[b * T_ + t]
                                      : mask_w[b * T_ + t];
            c += (mv != 0u) ? 1.f : 0.f;
        }
        atomicAdd(&s_cnt[b], c);
    }
    __syncthreads();
    if (tid < B_)   ws[tid] = s_cnt[tid];
    if (tid == 8)   ws[8]  = 0.f;
    if (tid == 9)   ws[9]  = 0.f;
    if (tid == 10)  ws[10] = 0.f;
    if (tid == 11)  ws[11] = (s_odd_or == 0u) ? 1.f : 0.f;  // all-odd-zero -> int64
    if (tid == 12)  ws[12] = (s_gt1_or != 0u) ? 1.f : 0.f;  // word>1 seen -> uint8
}

__global__ __launch_bounds__(256) void main_kernel(const float* __restrict__ gnn,
                                                   const float* __restrict__ text,
                                                   const float* __restrict__ scale_p,
                                                   const unsigned int* __restrict__ coords_w,
                                                   const unsigned int* __restrict__ mask_w,
                                                   float* __restrict__ ws)
{
    int tid  = threadIdx.x;
    int lane = tid & 63;
    int wid  = tid >> 6;                    // wave in block: 0..3
    int token = blockIdx.x * 4 + wid;       // 0..8191
    int b = token >> 10;
    int t = token & (T_ - 1);

    bool coords_i64 = (ws[11] != 0.f);
    bool mask_u8    = (ws[12] != 0.f);

    int idx = coords_i64 ? (int)coords_w[2 * token] : (int)coords_w[token];

    // Gathered GNN row: lane i holds float4 at d = 4*i (wave reads 1 KB contiguous)
    const float4* g4 = (const float4*)(gnn + ((size_t)b * NN + idx) * D_);
    float4 g = g4[lane];

    // 20 class rows, each 1 KB contiguous, strided 1 MB apart
    const float4* tb = (const float4*)(text + (((size_t)b * M1) * T_ + t) * D_) + lane;
    float s[M1];
#pragma unroll
    for (int m = 0; m < M1; ++m) {
        float4 tv = tb[(size_t)m * T_ * (D_ / 4)];
        s[m] = g.x * tv.x + g.y * tv.y + g.z * tv.z + g.w * tv.w;
    }

    // Butterfly reduce each class sum across the 64-lane wave
#pragma unroll
    for (int m = 0; m < M1; ++m) {
        float v = s[m];
        v += __shfl_xor(v, 1, 64);
        v += __shfl_xor(v, 2, 64);
        v += __shfl_xor(v, 4, 64);
        v += __shfl_xor(v, 8, 64);
        v += __shfl_xor(v, 16, 64);
        v += __shfl_xor(v, 32, 64);
        s[m] = v;
    }

    float scale = scale_p[0];
    float s0 = s[0] * scale;
    float mx = s0;
#pragma unroll
    for (int m = 1; m < M1; ++m) { s[m] *= scale; mx = fmaxf(mx, s[m]); }
    float sum = __expf(s0 - mx);
#pragma unroll
    for (int m = 1; m < M1; ++m) sum += __expf(s[m] - mx);
    float loss_tok = mx + __logf(sum) - s0;          // lse - s0
    float correct  = (s0 >= mx) ? 1.f : 0.f;         // argmax == 0 (first-max rule)

    unsigned int mv = mask_u8 ? (unsigned int)((const unsigned char*)mask_w)[token]
                              : mask_w[token];
    float mk = (mv != 0u) ? 1.f : 0.f;
    float rc = ws[b];
    float loss_c = mk * loss_tok / rc;
    float cor_c  = mk * correct;

    // Per-block reduction (4 waves) then 3 atomics per block
    __shared__ float sl[4], sc[4], sm[4];
    if (lane == 0) { sl[wid] = loss_c; sc[wid] = cor_c; sm[wid] = mk; }
    __syncthreads();
    if (tid == 0) {
        atomicAdd(&ws[8],  sl[0] + sl[1] + sl[2] + sl[3]);
        atomicAdd(&ws[9],  sc[0] + sc[1] + sc[2] + sc[3]);
        atomicAdd(&ws[10], sm[0] + sm[1] + sm[2] + sm[3]);
    }
}

__global__ void finalize_kernel(const float* __restrict__ ws, float* __restrict__ out)
{
    if (threadIdx.x == 0) {
        out[0] = ws[8] / (float)B_;
        out[1] = ws[9] / ws[10];
    }
}

extern "C" void kernel_launch(void* const* d_in, const int* in_sizes, int n_in,
                              void* d_out, int out_size, void* d_ws, size_t ws_size,
                              hipStream_t stream)
{
    const float* gnn          = (const float*)d_in[0];
    const float* text         = (const float*)d_in[1];
    const float* scale        = (const float*)d_in[2];
    const unsigned int* coords = (const unsigned int*)d_in[3];
    const unsigned int* mask   = (const unsigned int*)d_in[4];
    float* ws  = (float*)d_ws;
    float* out = (float*)d_out;

    setup_kernel<<<1, 256, 0, stream>>>(coords, mask, ws);
    main_kernel<<<(B_ * T_) / 4, 256, 0, stream>>>(gnn, text, scale, coords, mask, ws);
    finalize_kernel<<<1, 64, 0, stream>>>(ws, out);
}

// Round 2
// 43.457 us; speedup vs baseline: 5.8479x; 5.8479x over previous
//
#include <hip/hip_runtime.h>
#include <hip/hip_bf16.h>

#define B_  8
#define NN  2048
#define D_  256
#define T_  1024
#define M1  20   // NUM_MUT + 1 classes

#define NBLK ((B_ * T_) / 4)   // 2048 main-kernel blocks, 4 tokens (waves) each
#define BLK_PER_B (NBLK / B_)  // 256 blocks per batch row

// ws layout (floats):
//  [0]  coords-is-int64 flag
//  [1]  mask-is-uint8 flag
//  [16              .. 16+NBLK)   per-block loss partials   (mask*losstok, undivided)
//  [16+NBLK         .. 16+2*NBLK) per-block correct partials
//  [16+2*NBLK       .. 16+3*NBLK) per-block mask-count partials
#define PL 16
#define PC (16 + NBLK)
#define PM (16 + 2 * NBLK)

__global__ __launch_bounds__(256) void setup_kernel(const unsigned int* __restrict__ coords_w,
                                                    const unsigned int* __restrict__ mask_w,
                                                    float* __restrict__ ws)
{
    __shared__ unsigned int s_odd_or;   // nonzero -> coords is int32
    __shared__ unsigned int s_gt1_or;   // nonzero -> mask is uint8 (packed bools)
    int tid = threadIdx.x;
    if (tid == 0) { s_odd_or = 0u; s_gt1_or = 0u; }
    __syncthreads();

    // Coords width: int64 layout -> every odd 32-bit word (high half) is zero
    // (values 0..2047). int32 layout -> odd words are random coords.
    unsigned int odd = 0u;
    for (int i = tid; i < B_ * T_ / 2; i += 256) odd |= coords_w[2 * i + 1];
    // Mask layout: uint8-bool packs 4 ~80%-true bools per word -> some word > 1.
    // int32 layout -> all words are 0 or 1.
    unsigned int gt = 0u;
    for (int i = tid; i < B_ * T_ / 4; i += 256) gt |= (mask_w[i] > 1u) ? 1u : 0u;
    if (odd) atomicOr(&s_odd_or, 1u);
    if (gt)  atomicOr(&s_gt1_or, 1u);
    __syncthreads();

    if (tid == 0) ws[0] = (s_odd_or == 0u) ? 1.f : 0.f;
    if (tid == 1) ws[1] = (s_gt1_or != 0u) ? 1.f : 0.f;
}

__global__ __launch_bounds__(256) void main_kernel(const float* __restrict__ gnn,
                                                   const float* __restrict__ text,
                                                   const float* __restrict__ scale_p,
                                                   const unsigned int* __restrict__ coords_w,
                                                   const unsigned int* __restrict__ mask_w,
                                                   float* __restrict__ ws)
{
    int tid  = threadIdx.x;
    int lane = tid & 63;
    int wid  = tid >> 6;                    // wave in block: 0..3
    int token = blockIdx.x * 4 + wid;       // 0..8191; all 4 tokens share one b
    int b = token >> 10;
    int t = token & (T_ - 1);

    bool coords_i64 = (ws[0] != 0.f);
    bool mask_u8    = (ws[1] != 0.f);

    int idx = coords_i64 ? (int)coords_w[2 * token] : (int)coords_w[token];

    // Gathered GNN row: lane i holds float4 at d = 4*i (wave reads 1 KB contiguous)
    const float4* g4 = (const float4*)(gnn + ((size_t)b * NN + idx) * D_);
    float4 g = g4[lane];

    // 20 class rows, each 1 KB contiguous, strided 1 MB apart — 20 independent
    // dwordx4 loads in flight per wave.
    const float4* tb = (const float4*)(text + (((size_t)b * M1) * T_ + t) * D_) + lane;
    float s[M1];
#pragma unroll
    for (int m = 0; m < M1; ++m) {
        float4 tv = tb[(size_t)m * T_ * (D_ / 4)];
        s[m] = g.x * tv.x + g.y * tv.y + g.z * tv.z + g.w * tv.w;
    }

    // Butterfly reduce each class sum across the 64-lane wave (20 indep chains)
#pragma unroll
    for (int m = 0; m < M1; ++m) {
        float v = s[m];
        v += __shfl_xor(v, 1, 64);
        v += __shfl_xor(v, 2, 64);
        v += __shfl_xor(v, 4, 64);
        v += __shfl_xor(v, 8, 64);
        v += __shfl_xor(v, 16, 64);
        v += __shfl_xor(v, 32, 64);
        s[m] = v;
    }

    float scale = scale_p[0];
    float s0 = s[0] * scale;
    float mx = s0;
#pragma unroll
    for (int m = 1; m < M1; ++m) { s[m] *= scale; mx = fmaxf(mx, s[m]); }
    float sum = __expf(s0 - mx);
#pragma unroll
    for (int m = 1; m < M1; ++m) sum += __expf(s[m] - mx);
    float loss_tok = mx + __logf(sum) - s0;          // lse - s0
    float correct  = (s0 >= mx) ? 1.f : 0.f;         // argmax==0 (first-max rule)

    unsigned int mv = mask_u8 ? (unsigned int)((const unsigned char*)mask_w)[token]
                              : mask_w[token];
    float mk = (mv != 0u) ? 1.f : 0.f;

    // Per-block reduction (4 waves) -> NON-atomic per-block partial slots.
    // (R1 lesson: 6144 same-line device atomics serialized at ~40ns each = 248us.)
    __shared__ float sl[4], sc[4], sm[4];
    if (lane == 0) { sl[wid] = mk * loss_tok; sc[wid] = mk * correct; sm[wid] = mk; }
    __syncthreads();
    if (tid == 0) {
        ws[PL + blockIdx.x] = sl[0] + sl[1] + sl[2] + sl[3];
        ws[PC + blockIdx.x] = sc[0] + sc[1] + sc[2] + sc[3];
        ws[PM + blockIdx.x] = sm[0] + sm[1] + sm[2] + sm[3];
    }
}

// 8 waves, wave w reduces batch-row b=w's 256 block partials.
__global__ __launch_bounds__(512) void finalize_kernel(const float* __restrict__ ws,
                                                       float* __restrict__ out)
{
    int tid  = threadIdx.x;
    int lane = tid & 63;
    int b    = tid >> 6;   // 0..7

    float l = 0.f, c = 0.f, m = 0.f;
#pragma unroll
    for (int k = 0; k < BLK_PER_B / 64; ++k) {      // 4 elements per lane
        int i = b * BLK_PER_B + k * 64 + lane;
        l += ws[PL + i];
        c += ws[PC + i];
        m += ws[PM + i];
    }
#pragma unroll
    for (int d = 1; d < 64; d <<= 1) {
        l += __shfl_xor(l, d, 64);
        c += __shfl_xor(c, d, 64);
        m += __shfl_xor(m, d, 64);
    }

    __shared__ float sl[B_], sc[B_], sm[B_];
    if (lane == 0) { sl[b] = l / m; sc[b] = c; sm[b] = m; }
    __syncthreads();
    if (tid == 0) {
        float L = 0.f, C = 0.f, M = 0.f;
#pragma unroll
        for (int i = 0; i < B_; ++i) { L += sl[i]; C += sc[i]; M += sm[i]; }
        out[0] = L / (float)B_;
        out[1] = C / M;
    }
}

extern "C" void kernel_launch(void* const* d_in, const int* in_sizes, int n_in,
                              void* d_out, int out_size, void* d_ws, size_t ws_size,
                              hipStream_t stream)
{
    const float* gnn           = (const float*)d_in[0];
    const float* text          = (const float*)d_in[1];
    const float* scale         = (const float*)d_in[2];
    const unsigned int* coords = (const unsigned int*)d_in[3];
    const unsigned int* mask   = (const unsigned int*)d_in[4];
    float* ws  = (float*)d_ws;
    float* out = (float*)d_out;

    setup_kernel<<<1, 256, 0, stream>>>(coords, mask, ws);
    main_kernel<<<NBLK, 256, 0, stream>>>(gnn, text, scale, coords, mask, ws);
    finalize_kernel<<<1, 512, 0, stream>>>(ws, out);
}

// Round 3
// 38.688 us; speedup vs baseline: 6.5687x; 1.1233x over previous
//
#include <hip/hip_runtime.h>
#include <hip/hip_bf16.h>

#define B_  8
#define NN  2048
#define D_  256
#define T_  1024
#define M1  20   // NUM_MUT + 1 classes

#define TOK_PER_BLK 16
#define NBLK ((B_ * T_) / TOK_PER_BLK)   // 512 main blocks; 4 waves, 4 tokens/wave
#define BLK_PER_B (NBLK / B_)            // 64 blocks per batch row

// ws layout (floats):
//  [0]  coords-is-int64 flag
//  [1]  mask-is-uint8 flag
//  [16 .. 16+NBLK)              per-block loss partials (mask*losstok, undivided)
//  [16+NBLK .. 16+2*NBLK)       per-block correct partials
//  [16+2*NBLK .. 16+3*NBLK)     per-block mask-count partials
#define PL 16
#define PC (16 + NBLK)
#define PM (16 + 2 * NBLK)

__global__ __launch_bounds__(1024) void setup_kernel(const uint4* __restrict__ coords_v,
                                                     const uint4* __restrict__ mask_v,
                                                     float* __restrict__ ws)
{
    __shared__ unsigned int s_odd_or;   // nonzero -> coords is int32
    __shared__ unsigned int s_gt1_or;   // nonzero -> mask is uint8 (packed bools)
    int tid = threadIdx.x;
    if (tid == 0) { s_odd_or = 0u; s_gt1_or = 0u; }
    __syncthreads();

    // Coords: scan first 8192 32-bit words (32 KB — safe under BOTH layouts).
    // int64 layout -> odd words (high halves) all zero; int32 -> random 0..2047.
    unsigned int odd = 0u;
    {   // 8192 words = 2048 uint4; 1024 threads x 2
        uint4 a = coords_v[tid];
        uint4 b = coords_v[tid + 1024];
        odd = a.y | a.w | b.y | b.w;
    }
    // Mask: scan first 2048 words (8 KB — safe under both layouts).
    // uint8-bool packs 4 ~80%-true bytes/word -> some word > 1; int32 words are 0/1.
    unsigned int gt = 0u;
    if (tid < 512) {
        uint4 m = mask_v[tid];
        gt = (m.x > 1u) | (m.y > 1u) | (m.z > 1u) | (m.w > 1u);
    }
    if (odd) atomicOr(&s_odd_or, 1u);
    if (gt)  atomicOr(&s_gt1_or, 1u);
    __syncthreads();

    if (tid == 0) ws[0] = (s_odd_or == 0u) ? 1.f : 0.f;
    if (tid == 1) ws[1] = (s_gt1_or != 0u) ? 1.f : 0.f;
}

__device__ __forceinline__ float dot4(float4 a, float4 b) {
    return a.x * b.x + a.y * b.y + a.z * b.z + a.w * b.w;
}

// 16 lanes per token, 4 tokens per wave, 4 waves per block (16 tokens/block).
// Lane q holds floats [16q, 16q+16) of each 256-float row -> 4-stage reduce,
// 20 shuffles/token instead of 120 (R2 lesson: DS pipe was ~9us chip-wide).
__global__ __launch_bounds__(256) void main_kernel(const float* __restrict__ gnn,
                                                   const float* __restrict__ text,
                                                   const float* __restrict__ scale_p,
                                                   const unsigned int* __restrict__ coords_w,
                                                   const unsigned int* __restrict__ mask_w,
                                                   float* __restrict__ ws)
{
    int tid  = threadIdx.x;
    int lane = tid & 63;
    int wid  = tid >> 6;                    // wave in block: 0..3
    int p    = lane >> 4;                   // token subgroup in wave: 0..3
    int q    = lane & 15;                   // sublane within token: 0..15
    int token = blockIdx.x * TOK_PER_BLK + wid * 4 + p;
    int b = token >> 10;
    int t = token & (T_ - 1);

    bool coords_i64 = (ws[0] != 0.f);
    bool mask_u8    = (ws[1] != 0.f);

    int idx = coords_i64 ? (int)coords_w[2 * token] : (int)coords_w[token];

    // Gathered GNN row: lane q holds float4s [4q .. 4q+4)
    const float4* g4 = (const float4*)(gnn + ((size_t)b * NN + idx) * D_) + 4 * q;
    float4 g0 = g4[0], g1 = g4[1], g2 = g4[2], g3 = g4[3];

    // 20 class rows; each class = 4 dwordx4 per lane, fully independent -> ~80
    // loads of MLP per wave covers L3 latency at 8 waves/CU.
    const float4* tb = (const float4*)(text + (((size_t)b * M1) * T_ + t) * D_) + 4 * q;
    float s[M1];
#pragma unroll
    for (int m = 0; m < M1; ++m) {
        const float4* r = tb + (size_t)m * T_ * (D_ / 4);
        float4 t0 = r[0], t1 = r[1], t2 = r[2], t3 = r[3];
        s[m] = dot4(g0, t0) + dot4(g1, t1) + dot4(g2, t2) + dot4(g3, t3);
    }

    // 4-stage butterfly within each 16-lane group (xor 1,2,4,8 stay in-group)
#pragma unroll
    for (int m = 0; m < M1; ++m) {
        float v = s[m];
        v += __shfl_xor(v, 1, 64);
        v += __shfl_xor(v, 2, 64);
        v += __shfl_xor(v, 4, 64);
        v += __shfl_xor(v, 8, 64);
        s[m] = v;
    }

    float scale = scale_p[0];
    float s0 = s[0] * scale;
    float mx = s0;
#pragma unroll
    for (int m = 1; m < M1; ++m) { s[m] *= scale; mx = fmaxf(mx, s[m]); }
    float sum = __expf(s0 - mx);
#pragma unroll
    for (int m = 1; m < M1; ++m) sum += __expf(s[m] - mx);
    float loss_tok = mx + __logf(sum) - s0;          // lse - s0
    float correct  = (s0 >= mx) ? 1.f : 0.f;         // argmax==0 (first-max rule)

    unsigned int mv = mask_u8 ? (unsigned int)((const unsigned char*)mask_w)[token]
                              : mask_w[token];
    float mk = (mv != 0u) ? 1.f : 0.f;

    // Per-block reduction (16 token groups) -> non-atomic per-block partials
    __shared__ float sl[TOK_PER_BLK], sc[TOK_PER_BLK], sm[TOK_PER_BLK];
    if (q == 0) {
        int slot = wid * 4 + p;
        sl[slot] = mk * loss_tok; sc[slot] = mk * correct; sm[slot] = mk;
    }
    __syncthreads();
    if (tid == 0) {
        float L = 0.f, C = 0.f, M = 0.f;
#pragma unroll
        for (int i = 0; i < TOK_PER_BLK; ++i) { L += sl[i]; C += sc[i]; M += sm[i]; }
        ws[PL + blockIdx.x] = L;
        ws[PC + blockIdx.x] = C;
        ws[PM + blockIdx.x] = M;
    }
}

// 8 waves; wave b reduces batch-row b's 64 block partials (1 per lane).
__global__ __launch_bounds__(512) void finalize_kernel(const float* __restrict__ ws,
                                                       float* __restrict__ out)
{
    int tid  = threadIdx.x;
    int lane = tid & 63;
    int b    = tid >> 6;   // 0..7

    int i = b * BLK_PER_B + lane;
    float l = ws[PL + i];
    float c = ws[PC + i];
    float m = ws[PM + i];
#pragma unroll
    for (int d = 1; d < 64; d <<= 1) {
        l += __shfl_xor(l, d, 64);
        c += __shfl_xor(c, d, 64);
        m += __shfl_xor(m, d, 64);
    }

    __shared__ float sl[B_], sc[B_], sm[B_];
    if (lane == 0) { sl[b] = l / m; sc[b] = c; sm[b] = m; }
    __syncthreads();
    if (tid == 0) {
        float L = 0.f, C = 0.f, M = 0.f;
#pragma unroll
        for (int i2 = 0; i2 < B_; ++i2) { L += sl[i2]; C += sc[i2]; M += sm[i2]; }
        out[0] = L / (float)B_;
        out[1] = C / M;
    }
}

extern "C" void kernel_launch(void* const* d_in, const int* in_sizes, int n_in,
                              void* d_out, int out_size, void* d_ws, size_t ws_size,
                              hipStream_t stream)
{
    const float* gnn           = (const float*)d_in[0];
    const float* text          = (const float*)d_in[1];
    const float* scale         = (const float*)d_in[2];
    const unsigned int* coords = (const unsigned int*)d_in[3];
    const unsigned int* mask   = (const unsigned int*)d_in[4];
    float* ws  = (float*)d_ws;
    float* out = (float*)d_out;

    setup_kernel<<<1, 1024, 0, stream>>>((const uint4*)coords, (const uint4*)mask, ws);
    main_kernel<<<NBLK, 256, 0, stream>>>(gnn, text, scale, coords, mask, ws);
    finalize_kernel<<<1, 512, 0, stream>>>(ws, out);
}